// Round 6
// baseline (254.903 us; speedup 1.0000x reference)
//
#include <hip/hip_runtime.h>

#define N 65536
#define D 64
#define V 8192
#define LOSS_OFF (N * D)
#define IDX_OFF (N * D + 1)
#define MARGIN 0.02f

typedef _Float16 half8 __attribute__((ext_vector_type(8)));
typedef float f32x4 __attribute__((ext_vector_type(4)));

typedef __attribute__((address_space(1))) const void gas_t;
typedef __attribute__((address_space(3))) void las_t;

// 16-dim partial dot with named float4 regs (never an indexed array -> no scratch)
#define DOT16(s, A0, A1, A2, A3, B0, B1, B2, B3)                         \
    s = fmaf(A0.x, B0.x, s); s = fmaf(A0.y, B0.y, s);                    \
    s = fmaf(A0.z, B0.z, s); s = fmaf(A0.w, B0.w, s);                    \
    s = fmaf(A1.x, B1.x, s); s = fmaf(A1.y, B1.y, s);                    \
    s = fmaf(A1.z, B1.z, s); s = fmaf(A1.w, B1.w, s);                    \
    s = fmaf(A2.x, B2.x, s); s = fmaf(A2.y, B2.y, s);                    \
    s = fmaf(A2.z, B2.z, s); s = fmaf(A2.w, B2.w, s);                    \
    s = fmaf(A3.x, B3.x, s); s = fmaf(A3.y, B3.y, s);                    \
    s = fmaf(A3.z, B3.z, s); s = fmaf(A3.w, B3.w, s);

// order-preserving f32 -> u32 (finite values): min score == min encoding
__device__ __forceinline__ unsigned enc32(float f) {
    unsigned u = __float_as_uint(f);
    return (u & 0x80000000u) ? ~u : (u | 0x80000000u);
}

// ---------------- kernel 1: Ef16 = f16(-2E), e2 = sum E^2, zero scalars -----
__global__ void k_split(const float* __restrict__ E, _Float16* __restrict__ Ef16,
                        float* __restrict__ e2, float* __restrict__ dout,
                        int* __restrict__ fcount) {
    int v = blockIdx.x * 256 + threadIdx.x;
    if (v == 0) {
        dout[LOSS_OFF] = 0.0f;
        *fcount = 0;
    }
    if (v >= V) return;
    const float4* row = (const float4*)(E + (size_t)v * D);
    float s = 0.0f;
#pragma unroll
    for (int i = 0; i < 16; ++i) {
        float4 t = row[i];
        s += t.x * t.x + t.y * t.y + t.z * t.z + t.w * t.w;
    }
    e2[v] = s;
#pragma unroll
    for (int i = 0; i < 8; ++i) {
        float4 lo = row[i * 2];
        float4 hi = row[i * 2 + 1];
        half8 h;
        h[0] = (_Float16)(-2.0f * lo.x); h[1] = (_Float16)(-2.0f * lo.y);
        h[2] = (_Float16)(-2.0f * lo.z); h[3] = (_Float16)(-2.0f * lo.w);
        h[4] = (_Float16)(-2.0f * hi.x); h[5] = (_Float16)(-2.0f * hi.y);
        h[6] = (_Float16)(-2.0f * hi.z); h[7] = (_Float16)(-2.0f * hi.w);
        *(half8*)(Ef16 + (size_t)v * D + i * 8) = h;
    }
}

// ---------------- kernel 2: MFMA approx argmin, V-split x2, leaf=32 ---------
// grid = (N/128) x 2 partitions (bid&1). 256 thr = 4 waves; wave owns 32 rows.
// A = E-tile (16 entries), B = X rows. acc f32x4 = 4 consecutive entries of
// one x-row; exact-f32 e2 quad is the MFMA C-init. Leaf = 32 entries
// (ch,kg); one MERGE per chunk. Per-partition record {m1,m2,gid} -> part4.
#define MERGE(M1, M2, GID, L, PID)          \
    {                                       \
        bool bt = (L) < (M1);               \
        float m2c = bt ? (M1) : (L);        \
        (M2) = fminf((M2), m2c);            \
        (GID) = bt ? (PID) : (GID);         \
        (M1) = fminf((M1), (L));            \
    }

__global__ __launch_bounds__(256) void k_argmin(const float* __restrict__ X,
                                                const _Float16* __restrict__ Ef16,
                                                const float* __restrict__ e2,
                                                float4* __restrict__ part4) {
    __shared__ __align__(16) _Float16 els[2][8192];  // 2 x 16KB, swizzled
    __shared__ __align__(16) float e2ls[2][128];

    const int tid = threadIdx.x;
    const int lane = tid & 63;
    const int wave = tid >> 6;
    const int P = blockIdx.x & 1;          // V-partition
    const int rb = blockIdx.x >> 1;
    const int c4 = lane & 15;
    const int kg = lane >> 4;              // 0..3
    const int wrow = rb * 128 + wave * 32;
    const int sw = c4 & 7;
    const int k0off = (kg ^ sw) * 8;
    const int k1off = ((4 + kg) ^ sw) * 8;
    const int ch0 = P * 32;

    // B-frags: X rows (loop-invariant registers)
    half8 x00, x01, x10, x11;
    {
        const float* xr0 = X + (size_t)(wrow + c4) * D;
        const float* xr1 = X + (size_t)(wrow + 16 + c4) * D;
#pragma unroll
        for (int f = 0; f < 2; ++f) {
            float4 lo = *(const float4*)(xr0 + f * 32 + kg * 8);
            float4 hi = *(const float4*)(xr0 + f * 32 + kg * 8 + 4);
            half8 h;
            h[0] = (_Float16)lo.x; h[1] = (_Float16)lo.y;
            h[2] = (_Float16)lo.z; h[3] = (_Float16)lo.w;
            h[4] = (_Float16)hi.x; h[5] = (_Float16)hi.y;
            h[6] = (_Float16)hi.z; h[7] = (_Float16)hi.w;
            if (f == 0) x00 = h; else x01 = h;
        }
#pragma unroll
        for (int f = 0; f < 2; ++f) {
            float4 lo = *(const float4*)(xr1 + f * 32 + kg * 8);
            float4 hi = *(const float4*)(xr1 + f * 32 + kg * 8 + 4);
            half8 h;
            h[0] = (_Float16)lo.x; h[1] = (_Float16)lo.y;
            h[2] = (_Float16)lo.z; h[3] = (_Float16)lo.w;
            h[4] = (_Float16)hi.x; h[5] = (_Float16)hi.y;
            h[6] = (_Float16)hi.z; h[7] = (_Float16)hi.w;
            if (f == 0) x10 = h; else x11 = h;
        }
    }

    float m1a = 3.4e38f, m2a = 3.4e38f, m1b = 3.4e38f, m2b = 3.4e38f;
    unsigned gida = 0, gidb = 0;
    const unsigned kgu = (unsigned)kg;

#define STAGE(BUF, CH)                                                        \
    {                                                                         \
        _Pragma("unroll") for (int it = 0; it < 4; ++it) {                    \
            int q = it * 256 + tid;                                           \
            int c = q >> 3, p = q & 7, j = p ^ (c & 7);                       \
            const _Float16* src =                                             \
                Ef16 + ((size_t)((CH)*128 + c) * D + j * 8);                  \
            __builtin_amdgcn_global_load_lds((gas_t*)src,                     \
                                             (las_t*)&els[BUF][q * 8], 16, 0, \
                                             0);                              \
        }                                                                     \
        if (tid < 32) {                                                       \
            const float* s2 = e2 + (CH)*128 + tid * 4;                        \
            __builtin_amdgcn_global_load_lds(                                 \
                (gas_t*)s2, (las_t*)&e2ls[BUF][tid * 4], 16, 0, 0);           \
        }                                                                     \
    }

    STAGE(0, ch0)

    for (int ci = 0; ci < 32; ++ci) {
        const int ch = ch0 + ci;
        __syncthreads();  // drains prior STAGE (vmcnt) + protects buf reuse
        if (ci < 31) STAGE((ci + 1) & 1, ch + 1)
        const int buf = ci & 1;

        float La = 3.4e38f, Lb = 3.4e38f;
#pragma unroll
        for (int t = 0; t < 8; ++t) {
            const f32x4 e2q = *(const f32x4*)&e2ls[buf][t * 16 + kg * 4];
            const half8 a0 = *(const half8*)&els[buf][(t * 16 + c4) * 64 + k0off];
            const half8 a1 = *(const half8*)&els[buf][(t * 16 + c4) * 64 + k1off];

            f32x4 acc0 = __builtin_amdgcn_mfma_f32_16x16x32_f16(a0, x00, e2q, 0, 0, 0);
            acc0 = __builtin_amdgcn_mfma_f32_16x16x32_f16(a1, x01, acc0, 0, 0, 0);
            f32x4 acc1 = __builtin_amdgcn_mfma_f32_16x16x32_f16(a0, x10, e2q, 0, 0, 0);
            acc1 = __builtin_amdgcn_mfma_f32_16x16x32_f16(a1, x11, acc1, 0, 0, 0);

            La = fminf(fminf(La, fminf(acc0[0], acc0[1])), fminf(acc0[2], acc0[3]));
            Lb = fminf(fminf(Lb, fminf(acc1[0], acc1[1])), fminf(acc1[2], acc1[3]));
        }
        // leaf = 32 entries {ch*128 + t*16 + kg*4 + j}
        unsigned pid = (unsigned)(ch * 4) + kgu;
        MERGE(m1a, m2a, gida, La, pid)
        MERGE(m1b, m2b, gidb, Lb, pid)
    }

    // merge the 4 kg lane-groups (lanes l, l+16, l+32, l+48 share an x-row)
#pragma unroll
    for (int off = 16; off < 64; off <<= 1) {
        float o1, o2;
        unsigned og;
        o1 = __shfl_xor(m1a, off, 64); o2 = __shfl_xor(m2a, off, 64);
        og = (unsigned)__shfl_xor((int)gida, off, 64);
        m2a = fminf(fminf(fmaxf(m1a, o1), m2a), o2);
        if (o1 < m1a) gida = og;
        m1a = fminf(m1a, o1);
        o1 = __shfl_xor(m1b, off, 64); o2 = __shfl_xor(m2b, off, 64);
        og = (unsigned)__shfl_xor((int)gidb, off, 64);
        m2b = fminf(fminf(fmaxf(m1b, o1), m2b), o2);
        if (o1 < m1b) gidb = og;
        m1b = fminf(m1b, o1);
    }

    if (lane < 16) {
        float4 r;
        r.x = m1a; r.y = m2a; r.z = __uint_as_float(gida); r.w = 0.0f;
        part4[(size_t)P * N + wrow + lane] = r;
        r.x = m1b; r.y = m2b; r.z = __uint_as_float(gidb);
        part4[(size_t)P * N + wrow + 16 + lane] = r;
    }
}

// ---------------- kernel 3: merge partitions + exact 32-entry leaf scan -----
// one wave per row. flagged rows: compact into flist for k_full.
__global__ __launch_bounds__(256) void k_group(const float* __restrict__ X,
                                               const float* __restrict__ E,
                                               const float* __restrict__ e2,
                                               const float4* __restrict__ part4,
                                               unsigned* __restrict__ gidw,
                                               int* __restrict__ fcount,
                                               int* __restrict__ flist,
                                               unsigned long long* __restrict__ packed,
                                               float* __restrict__ dout) {
    const int lane = threadIdx.x & 63;
    const int row = blockIdx.x * 4 + (threadIdx.x >> 6);

    const float4 ra = part4[row];
    const float4 rbp = part4[N + row];
    const float m1a = ra.x, m2a = ra.y;
    const float m1b = rbp.x, m2b = rbp.y;
    const unsigned ga = __float_as_uint(ra.z);
    const unsigned gb = __float_as_uint(rbp.z);
    // top-2 merge: m2 = best approx score OUTSIDE the winning leaf
    const float m1 = fminf(m1a, m1b);
    const float m2 = fminf(fminf(m2a, m2b), fmaxf(m1a, m1b));
    const unsigned g = (m1b < m1a) ? gb : ga;

    if (m2 - m1 < MARGIN) {  // conservative: ties & close calls -> exact scan
        if (lane == 0) {
            int p = atomicAdd(fcount, 1);
            flist[p] = row;
            packed[p] = ~0ull;
            gidw[row] = ((unsigned)p << 1) | 1u;
        }
        return;
    }
    if (lane == 0) gidw[row] = 0;

    // exact f32 rescan of winning leaf: v = ch*128 + (s>>2)*16 + kg*4 + (s&3)
    const int ch = (int)(g >> 2);
    const int kgr = (int)(g & 3);
    const int e4 = lane >> 2;
    const int dg = lane & 3;
    const float4* xp = (const float4*)(X + (size_t)row * D) + dg * 4;
    float4 xa0 = xp[0], xa1 = xp[1], xa2 = xp[2], xa3 = xp[3];

    float best = 3.4e38f;
    int bidx = 0x7fffffff;
#pragma unroll
    for (int it = 0; it < 2; ++it) {
        const int s = it * 16 + e4;  // strictly increasing entry index
        const int v = ch * 128 + ((s >> 2) << 4) + kgr * 4 + (s & 3);
        const float4* ep = (const float4*)(E + (size_t)v * D) + dg * 4;
        float4 b0 = ep[0], b1 = ep[1], b2 = ep[2], b3 = ep[3];
        float s0 = 0.0f;
        DOT16(s0, xa0, xa1, xa2, xa3, b0, b1, b2, b3)
        s0 += __shfl_xor(s0, 1, 64);
        s0 += __shfl_xor(s0, 2, 64);
        float d = fmaf(-2.0f, s0, e2[v]);
        if (d < best) { best = d; bidx = v; }
    }
#pragma unroll
    for (int off = 4; off < 64; off <<= 1) {
        float ob = __shfl_xor(best, off, 64);
        int oi = __shfl_xor(bidx, off, 64);
        if (ob < best || (ob == best && oi < bidx)) { best = ob; bidx = oi; }
    }
    if (lane == 0) dout[IDX_OFF + row] = (float)bidx;
}

// ---------------- kernel 4: exact full scan for FLAGGED rows ----------------
// work item = (row-quad, 1/8 chunk of V); grid-stride; atomicMin u64 merge.
__global__ __launch_bounds__(256) void k_full(const float* __restrict__ X,
                                              const float* __restrict__ E,
                                              const float* __restrict__ e2,
                                              const int* __restrict__ fcount,
                                              const int* __restrict__ flist,
                                              unsigned long long* __restrict__ packed) {
    const int nf = *fcount;
    if (nf == 0) return;
    const int nq = (nf + 3) >> 2;
    const int total = nq * 8;
    const int lane = threadIdx.x & 63;
    const int nwaves = gridDim.x * 4;
    int item = blockIdx.x * 4 + (threadIdx.x >> 6);
    const int e4 = lane >> 2;
    const int dg = lane & 3;

    for (; item < total; item += nwaves) {
        const int qi = item >> 3;
        const int c = item & 7;
        const int f0 = qi * 4;
        const int f1 = min(f0 + 1, nf - 1);
        const int f2 = min(f0 + 2, nf - 1);
        const int f3 = min(f0 + 3, nf - 1);
        const int r0 = flist[f0], r1 = flist[f1], r2 = flist[f2], r3 = flist[f3];

        const float4* xp0 = (const float4*)(X + (size_t)r0 * D) + dg * 4;
        const float4* xp1 = (const float4*)(X + (size_t)r1 * D) + dg * 4;
        const float4* xp2 = (const float4*)(X + (size_t)r2 * D) + dg * 4;
        const float4* xp3 = (const float4*)(X + (size_t)r3 * D) + dg * 4;
        float4 xa0 = xp0[0], xa1 = xp0[1], xa2 = xp0[2], xa3 = xp0[3];
        float4 xb0 = xp1[0], xb1 = xp1[1], xb2 = xp1[2], xb3 = xp1[3];
        float4 xc0 = xp2[0], xc1 = xp2[1], xc2 = xp2[2], xc3 = xp2[3];
        float4 xd0 = xp3[0], xd1 = xp3[1], xd2 = xp3[2], xd3 = xp3[3];

        unsigned long long k0 = ~0ull, k1 = ~0ull, k2 = ~0ull, k3 = ~0ull;

#pragma unroll 2
        for (int it = 0; it < 64; ++it) {
            const int v = c * 1024 + it * 16 + e4;
            const float4* ep = (const float4*)(E + (size_t)v * D) + dg * 4;
            float4 b0 = ep[0], b1 = ep[1], b2 = ep[2], b3 = ep[3];
            float s0 = 0.0f, s1 = 0.0f, s2 = 0.0f, s3 = 0.0f;
            DOT16(s0, xa0, xa1, xa2, xa3, b0, b1, b2, b3)
            DOT16(s1, xb0, xb1, xb2, xb3, b0, b1, b2, b3)
            DOT16(s2, xc0, xc1, xc2, xc3, b0, b1, b2, b3)
            DOT16(s3, xd0, xd1, xd2, xd3, b0, b1, b2, b3)
            s0 += __shfl_xor(s0, 1, 64); s0 += __shfl_xor(s0, 2, 64);
            s1 += __shfl_xor(s1, 1, 64); s1 += __shfl_xor(s1, 2, 64);
            s2 += __shfl_xor(s2, 1, 64); s2 += __shfl_xor(s2, 2, 64);
            s3 += __shfl_xor(s3, 1, 64); s3 += __shfl_xor(s3, 2, 64);
            const float ev = e2[v];
            const unsigned long long vb = (unsigned long long)(unsigned)v;
            unsigned long long t;
            t = ((unsigned long long)enc32(fmaf(-2.0f, s0, ev)) << 32) | vb;
            k0 = t < k0 ? t : k0;
            t = ((unsigned long long)enc32(fmaf(-2.0f, s1, ev)) << 32) | vb;
            k1 = t < k1 ? t : k1;
            t = ((unsigned long long)enc32(fmaf(-2.0f, s2, ev)) << 32) | vb;
            k2 = t < k2 ? t : k2;
            t = ((unsigned long long)enc32(fmaf(-2.0f, s3, ev)) << 32) | vb;
            k3 = t < k3 ? t : k3;
        }

#pragma unroll
        for (int off = 4; off < 64; off <<= 1) {
            unsigned lo, hi;
            unsigned long long o;
            lo = __shfl_xor((unsigned)k0, off, 64); hi = __shfl_xor((unsigned)(k0 >> 32), off, 64);
            o = ((unsigned long long)hi << 32) | lo; k0 = o < k0 ? o : k0;
            lo = __shfl_xor((unsigned)k1, off, 64); hi = __shfl_xor((unsigned)(k1 >> 32), off, 64);
            o = ((unsigned long long)hi << 32) | lo; k1 = o < k1 ? o : k1;
            lo = __shfl_xor((unsigned)k2, off, 64); hi = __shfl_xor((unsigned)(k2 >> 32), off, 64);
            o = ((unsigned long long)hi << 32) | lo; k2 = o < k2 ? o : k2;
            lo = __shfl_xor((unsigned)k3, off, 64); hi = __shfl_xor((unsigned)(k3 >> 32), off, 64);
            o = ((unsigned long long)hi << 32) | lo; k3 = o < k3 ? o : k3;
        }

        if (lane == 0) {
            atomicMin(&packed[f0], k0);
            atomicMin(&packed[f1], k1);
            atomicMin(&packed[f2], k2);
            atomicMin(&packed[f3], k3);
        }
    }
}

// ---------------- kernel 5: gather + STE output + loss ----------------------
__global__ void k_out(const float* __restrict__ X, const float* __restrict__ E,
                      const unsigned* __restrict__ gidw,
                      const unsigned long long* __restrict__ packed,
                      float* __restrict__ dout) {
    const int t = blockIdx.x * 256 + threadIdx.x;
    const int n = t >> 4;
    const int d = (t & 15) * 4;
    const unsigned g = gidw[n];
    int idx;
    if (g & 1) {
        idx = (int)(unsigned)(packed[g >> 1] & 0xffffffffull);
        if (d == 0) dout[IDX_OFF + n] = (float)idx;
    } else {
        idx = (int)dout[IDX_OFF + n];
    }
    float4 x4 = *(const float4*)(X + (size_t)n * D + d);
    float4 q4 = *(const float4*)(E + (size_t)idx * D + d);
    float4 o;
    o.x = x4.x + (q4.x - x4.x);
    o.y = x4.y + (q4.y - x4.y);
    o.z = x4.z + (q4.z - x4.z);
    o.w = x4.w + (q4.w - x4.w);
    *(float4*)(dout + (size_t)n * D + d) = o;

    float dx = q4.x - x4.x, dy = q4.y - x4.y, dz = q4.z - x4.z,
          dw = q4.w - x4.w;
    float s = dx * dx + dy * dy + dz * dz + dw * dw;
#pragma unroll
    for (int off = 32; off; off >>= 1) s += __shfl_down(s, off, 64);
    __shared__ float ps[4];
    if ((threadIdx.x & 63) == 0) ps[threadIdx.x >> 6] = s;
    __syncthreads();
    if (threadIdx.x == 0) {
        float tot = ps[0] + ps[1] + ps[2] + ps[3];
        atomicAdd(dout + LOSS_OFF, tot * (1.25f / ((float)N * (float)D)));
    }
}

extern "C" void kernel_launch(void* const* d_in, const int* in_sizes, int n_in,
                              void* d_out, int out_size, void* d_ws,
                              size_t ws_size, hipStream_t stream) {
    const float* X = (const float*)d_in[0];
    const float* E = (const float*)d_in[1];
    float* out = (float*)d_out;

    char* ws = (char*)d_ws;
    _Float16* Ef16 = (_Float16*)ws;                                   // 1 MB
    float* e2 = (float*)(ws + 1048576);                               // 32 KB
    unsigned* gidw = (unsigned*)(ws + 1081344);                       // 256 KB
    int* fcount = (int*)(ws + 1343488);                               // 256 B
    int* flist = (int*)(ws + 1343744);                                // 256 KB
    unsigned long long* packed = (unsigned long long*)(ws + 1605888); // 512 KB
    float4* part4 = (float4*)(ws + 2130176);                          // 2 MB

    k_split<<<V / 256, 256, 0, stream>>>(E, Ef16, e2, out, fcount);
    k_argmin<<<(N / 128) * 2, 256, 0, stream>>>(X, Ef16, e2, part4);
    k_group<<<N / 4, 256, 0, stream>>>(X, E, e2, part4, gidw, fcount, flist, packed, out);
    k_full<<<1024, 256, 0, stream>>>(X, E, e2, fcount, flist, packed);
    k_out<<<(N * 16) / 256, 256, 0, stream>>>(X, E, gidw, packed, out);
}

// Round 7
// 210.710 us; speedup vs baseline: 1.2097x; 1.2097x over previous
//
#include <hip/hip_runtime.h>

#define N 65536
#define D 64
#define V 8192
#define LOSS_OFF (N * D)
#define IDX_OFF (N * D + 1)
#define MARGIN 0.02f

typedef _Float16 half8 __attribute__((ext_vector_type(8)));
typedef float f32x4 __attribute__((ext_vector_type(4)));

typedef __attribute__((address_space(1))) const void gas_t;
typedef __attribute__((address_space(3))) void las_t;

// 16-dim partial dot with named float4 regs (never an indexed array -> no scratch)
#define DOT16(s, A0, A1, A2, A3, B0, B1, B2, B3)                         \
    s = fmaf(A0.x, B0.x, s); s = fmaf(A0.y, B0.y, s);                    \
    s = fmaf(A0.z, B0.z, s); s = fmaf(A0.w, B0.w, s);                    \
    s = fmaf(A1.x, B1.x, s); s = fmaf(A1.y, B1.y, s);                    \
    s = fmaf(A1.z, B1.z, s); s = fmaf(A1.w, B1.w, s);                    \
    s = fmaf(A2.x, B2.x, s); s = fmaf(A2.y, B2.y, s);                    \
    s = fmaf(A2.z, B2.z, s); s = fmaf(A2.w, B2.w, s);                    \
    s = fmaf(A3.x, B3.x, s); s = fmaf(A3.y, B3.y, s);                    \
    s = fmaf(A3.z, B3.z, s); s = fmaf(A3.w, B3.w, s);

// order-preserving f32 -> u32 (finite values): min score == min encoding
__device__ __forceinline__ unsigned enc32(float f) {
    unsigned u = __float_as_uint(f);
    return (u & 0x80000000u) ? ~u : (u | 0x80000000u);
}

// ---------------- kernel 1: Ef16 = f16(-2E), e2 = sum E^2, zero scalars -----
__global__ void k_split(const float* __restrict__ E, _Float16* __restrict__ Ef16,
                        float* __restrict__ e2, float* __restrict__ dout,
                        int* __restrict__ fcount) {
    int v = blockIdx.x * 256 + threadIdx.x;
    if (v == 0) {
        dout[LOSS_OFF] = 0.0f;
        *fcount = 0;
    }
    if (v >= V) return;
    const float4* row = (const float4*)(E + (size_t)v * D);
    float s = 0.0f;
#pragma unroll
    for (int i = 0; i < 16; ++i) {
        float4 t = row[i];
        s += t.x * t.x + t.y * t.y + t.z * t.z + t.w * t.w;
    }
    e2[v] = s;
#pragma unroll
    for (int i = 0; i < 8; ++i) {
        float4 lo = row[i * 2];
        float4 hi = row[i * 2 + 1];
        half8 h;
        h[0] = (_Float16)(-2.0f * lo.x); h[1] = (_Float16)(-2.0f * lo.y);
        h[2] = (_Float16)(-2.0f * lo.z); h[3] = (_Float16)(-2.0f * lo.w);
        h[4] = (_Float16)(-2.0f * hi.x); h[5] = (_Float16)(-2.0f * hi.y);
        h[6] = (_Float16)(-2.0f * hi.z); h[7] = (_Float16)(-2.0f * hi.w);
        *(half8*)(Ef16 + (size_t)v * D + i * 8) = h;
    }
}

// ---------------- kernel 2: MFMA approx argmin, V-split x2, leaf=32 ---------
// grid = (N/128) x 2 partitions (bid&1). 256 thr = 4 waves; wave owns 32 rows.
// A = E-tile (16 entries), B = X rows. acc f32x4 = 4 consecutive entries of
// one x-row; exact-f32 e2 quad (global dwordx4, L2-hit) is the MFMA C-init.
// Leaf = 32 entries (ch,kg); one MERGE per chunk -> {m1,m2,gid} per row.
#define MERGE(M1, M2, GID, L, PID)          \
    {                                       \
        bool bt = (L) < (M1);               \
        float m2c = bt ? (M1) : (L);        \
        (M2) = fminf((M2), m2c);            \
        (GID) = bt ? (PID) : (GID);         \
        (M1) = fminf((M1), (L));            \
    }

__global__ __launch_bounds__(256) void k_argmin(const float* __restrict__ X,
                                                const _Float16* __restrict__ Ef16,
                                                const float* __restrict__ e2,
                                                float4* __restrict__ part4) {
    __shared__ __align__(16) _Float16 els[2][8192];  // exactly 32 KB

    const int tid = threadIdx.x;
    const int lane = tid & 63;
    const int wave = tid >> 6;
    const int P = blockIdx.x & 1;          // V-partition
    const int rb = blockIdx.x >> 1;
    const int c4 = lane & 15;
    const int kg = lane >> 4;              // 0..3
    const int wrow = rb * 128 + wave * 32;
    const int sw = c4 & 7;
    const int k0off = (kg ^ sw) * 8;
    const int k1off = ((4 + kg) ^ sw) * 8;
    const int ch0 = P * 32;

    // B-frags: X rows (loop-invariant registers)
    half8 x00, x01, x10, x11;
    {
        const float* xr0 = X + (size_t)(wrow + c4) * D;
        const float* xr1 = X + (size_t)(wrow + 16 + c4) * D;
#pragma unroll
        for (int f = 0; f < 2; ++f) {
            float4 lo = *(const float4*)(xr0 + f * 32 + kg * 8);
            float4 hi = *(const float4*)(xr0 + f * 32 + kg * 8 + 4);
            half8 h;
            h[0] = (_Float16)lo.x; h[1] = (_Float16)lo.y;
            h[2] = (_Float16)lo.z; h[3] = (_Float16)lo.w;
            h[4] = (_Float16)hi.x; h[5] = (_Float16)hi.y;
            h[6] = (_Float16)hi.z; h[7] = (_Float16)hi.w;
            if (f == 0) x00 = h; else x01 = h;
        }
#pragma unroll
        for (int f = 0; f < 2; ++f) {
            float4 lo = *(const float4*)(xr1 + f * 32 + kg * 8);
            float4 hi = *(const float4*)(xr1 + f * 32 + kg * 8 + 4);
            half8 h;
            h[0] = (_Float16)lo.x; h[1] = (_Float16)lo.y;
            h[2] = (_Float16)lo.z; h[3] = (_Float16)lo.w;
            h[4] = (_Float16)hi.x; h[5] = (_Float16)hi.y;
            h[6] = (_Float16)hi.z; h[7] = (_Float16)hi.w;
            if (f == 0) x10 = h; else x11 = h;
        }
    }

    // staging: 4 named per-thread global pointers, fixed LDS offsets; all
    // swizzle math hoisted out of the loop. src advances 8192 halves/chunk.
    const int q0 = tid, q1 = tid + 256, q2 = tid + 512, q3 = tid + 768;
    const _Float16* gs0 = Ef16 + (size_t)(ch0 * 128 + (q0 >> 3)) * 64 + ((q0 & 7) ^ ((q0 >> 3) & 7)) * 8;
    const _Float16* gs1 = Ef16 + (size_t)(ch0 * 128 + (q1 >> 3)) * 64 + ((q1 & 7) ^ ((q1 >> 3) & 7)) * 8;
    const _Float16* gs2 = Ef16 + (size_t)(ch0 * 128 + (q2 >> 3)) * 64 + ((q2 & 7) ^ ((q2 >> 3) & 7)) * 8;
    const _Float16* gs3 = Ef16 + (size_t)(ch0 * 128 + (q3 >> 3)) * 64 + ((q3 & 7) ^ ((q3 >> 3) & 7)) * 8;
    const int ld0 = q0 * 8, ld1 = q1 * 8, ld2 = q2 * 8, ld3 = q3 * 8;

#define STAGE(BUF)                                                            \
    {                                                                         \
        __builtin_amdgcn_global_load_lds((gas_t*)gs0, (las_t*)&els[BUF][ld0], 16, 0, 0); \
        __builtin_amdgcn_global_load_lds((gas_t*)gs1, (las_t*)&els[BUF][ld1], 16, 0, 0); \
        __builtin_amdgcn_global_load_lds((gas_t*)gs2, (las_t*)&els[BUF][ld2], 16, 0, 0); \
        __builtin_amdgcn_global_load_lds((gas_t*)gs3, (las_t*)&els[BUF][ld3], 16, 0, 0); \
        gs0 += 8192; gs1 += 8192; gs2 += 8192; gs3 += 8192;                   \
    }

    float m1a = 3.4e38f, m2a = 3.4e38f, m1b = 3.4e38f, m2b = 3.4e38f;
    unsigned gida = 0, gidb = 0;
    const unsigned kgu = (unsigned)kg;

    // sequential fmin chains -> v_min3 fusion (2 instr per 4 scores + carry)
#define TSTEP(T, E2Q)                                                         \
    {                                                                         \
        const half8 a0 = *(const half8*)&els[buf][(T * 16 + c4) * 64 + k0off];\
        const half8 a1 = *(const half8*)&els[buf][(T * 16 + c4) * 64 + k1off];\
        f32x4 acc0 = __builtin_amdgcn_mfma_f32_16x16x32_f16(a0, x00, E2Q, 0, 0, 0); \
        acc0 = __builtin_amdgcn_mfma_f32_16x16x32_f16(a1, x01, acc0, 0, 0, 0);\
        f32x4 acc1 = __builtin_amdgcn_mfma_f32_16x16x32_f16(a0, x10, E2Q, 0, 0, 0); \
        acc1 = __builtin_amdgcn_mfma_f32_16x16x32_f16(a1, x11, acc1, 0, 0, 0);\
        La = fminf(fminf(fminf(fminf(La, acc0[0]), acc0[1]), acc0[2]), acc0[3]); \
        Lb = fminf(fminf(fminf(fminf(Lb, acc1[0]), acc1[1]), acc1[2]), acc1[3]); \
    }

    STAGE(0)
    const f32x4* e2p = (const f32x4*)(e2 + (size_t)ch0 * 128) + kg;

    for (int ci = 0; ci < 32; ++ci) {
        __syncthreads();  // drains prior STAGE (vmcnt0) + protects buf reuse
        // e2 quads FIRST (FIFO vmcnt: their wait must not drain next STAGE)
        const f32x4 e2q0 = e2p[0],  e2q1 = e2p[4],  e2q2 = e2p[8],  e2q3 = e2p[12];
        const f32x4 e2q4 = e2p[16], e2q5 = e2p[20], e2q6 = e2p[24], e2q7 = e2p[28];
        e2p += 32;
        if (ci < 31) STAGE((ci + 1) & 1)
        const int buf = ci & 1;

        float La = 3.4e38f, Lb = 3.4e38f;
        TSTEP(0, e2q0) TSTEP(1, e2q1) TSTEP(2, e2q2) TSTEP(3, e2q3)
        TSTEP(4, e2q4) TSTEP(5, e2q5) TSTEP(6, e2q6) TSTEP(7, e2q7)

        // leaf = 32 entries {ch*128 + t*16 + kg*4 + j}
        unsigned pid = (unsigned)((ch0 + ci) * 4) + kgu;
        MERGE(m1a, m2a, gida, La, pid)
        MERGE(m1b, m2b, gidb, Lb, pid)
    }

    // merge the 4 kg lane-groups (lanes l, l+16, l+32, l+48 share an x-row)
#pragma unroll
    for (int off = 16; off < 64; off <<= 1) {
        float o1, o2;
        unsigned og;
        o1 = __shfl_xor(m1a, off, 64); o2 = __shfl_xor(m2a, off, 64);
        og = (unsigned)__shfl_xor((int)gida, off, 64);
        m2a = fminf(fminf(fmaxf(m1a, o1), m2a), o2);
        if (o1 < m1a) gida = og;
        m1a = fminf(m1a, o1);
        o1 = __shfl_xor(m1b, off, 64); o2 = __shfl_xor(m2b, off, 64);
        og = (unsigned)__shfl_xor((int)gidb, off, 64);
        m2b = fminf(fminf(fmaxf(m1b, o1), m2b), o2);
        if (o1 < m1b) gidb = og;
        m1b = fminf(m1b, o1);
    }

    if (lane < 16) {
        float4 r;
        r.x = m1a; r.y = m2a; r.z = __uint_as_float(gida); r.w = 0.0f;
        part4[(size_t)P * N + wrow + lane] = r;
        r.x = m1b; r.y = m2b; r.z = __uint_as_float(gidb);
        part4[(size_t)P * N + wrow + 16 + lane] = r;
    }
}

// ---------------- kernel 3: merge partitions + exact 32-entry leaf scan -----
// one wave per row. flagged rows: compact into flist for k_full.
__global__ __launch_bounds__(256) void k_group(const float* __restrict__ X,
                                               const float* __restrict__ E,
                                               const float* __restrict__ e2,
                                               const float4* __restrict__ part4,
                                               unsigned* __restrict__ gidw,
                                               int* __restrict__ fcount,
                                               int* __restrict__ flist,
                                               unsigned long long* __restrict__ packed,
                                               float* __restrict__ dout) {
    const int lane = threadIdx.x & 63;
    const int row = blockIdx.x * 4 + (threadIdx.x >> 6);

    const float4 ra = part4[row];
    const float4 rbp = part4[N + row];
    const float m1a = ra.x, m2a = ra.y;
    const float m1b = rbp.x, m2b = rbp.y;
    const unsigned ga = __float_as_uint(ra.z);
    const unsigned gb = __float_as_uint(rbp.z);
    // top-2 merge: m2 = best approx score OUTSIDE the winning leaf
    const float m1 = fminf(m1a, m1b);
    const float m2 = fminf(fminf(m2a, m2b), fmaxf(m1a, m1b));
    const unsigned g = (m1b < m1a) ? gb : ga;

    if (m2 - m1 < MARGIN) {  // conservative: ties & close calls -> exact scan
        if (lane == 0) {
            int p = atomicAdd(fcount, 1);
            flist[p] = row;
            packed[p] = ~0ull;
            gidw[row] = ((unsigned)p << 1) | 1u;
        }
        return;
    }
    if (lane == 0) gidw[row] = 0;

    // exact f32 rescan of winning leaf: v = ch*128 + (s>>2)*16 + kg*4 + (s&3)
    const int ch = (int)(g >> 2);
    const int kgr = (int)(g & 3);
    const int e4 = lane >> 2;
    const int dg = lane & 3;
    const float4* xp = (const float4*)(X + (size_t)row * D) + dg * 4;
    float4 xa0 = xp[0], xa1 = xp[1], xa2 = xp[2], xa3 = xp[3];

    float best = 3.4e38f;
    int bidx = 0x7fffffff;
#pragma unroll
    for (int it = 0; it < 2; ++it) {
        const int s = it * 16 + e4;  // strictly increasing entry index
        const int v = ch * 128 + ((s >> 2) << 4) + kgr * 4 + (s & 3);
        const float4* ep = (const float4*)(E + (size_t)v * D) + dg * 4;
        float4 b0 = ep[0], b1 = ep[1], b2 = ep[2], b3 = ep[3];
        float s0 = 0.0f;
        DOT16(s0, xa0, xa1, xa2, xa3, b0, b1, b2, b3)
        s0 += __shfl_xor(s0, 1, 64);
        s0 += __shfl_xor(s0, 2, 64);
        float d = fmaf(-2.0f, s0, e2[v]);
        if (d < best) { best = d; bidx = v; }
    }
#pragma unroll
    for (int off = 4; off < 64; off <<= 1) {
        float ob = __shfl_xor(best, off, 64);
        int oi = __shfl_xor(bidx, off, 64);
        if (ob < best || (ob == best && oi < bidx)) { best = ob; bidx = oi; }
    }
    if (lane == 0) dout[IDX_OFF + row] = (float)bidx;
}

// ---------------- kernel 4: exact full scan for FLAGGED rows ----------------
// work item = (row-quad, 1/8 chunk of V); grid-stride; atomicMin u64 merge.
__global__ __launch_bounds__(256) void k_full(const float* __restrict__ X,
                                              const float* __restrict__ E,
                                              const float* __restrict__ e2,
                                              const int* __restrict__ fcount,
                                              const int* __restrict__ flist,
                                              unsigned long long* __restrict__ packed) {
    const int nf = *fcount;
    if (nf == 0) return;
    const int nq = (nf + 3) >> 2;
    const int total = nq * 8;
    const int lane = threadIdx.x & 63;
    const int nwaves = gridDim.x * 4;
    int item = blockIdx.x * 4 + (threadIdx.x >> 6);
    const int e4 = lane >> 2;
    const int dg = lane & 3;

    for (; item < total; item += nwaves) {
        const int qi = item >> 3;
        const int c = item & 7;
        const int f0 = qi * 4;
        const int f1 = min(f0 + 1, nf - 1);
        const int f2 = min(f0 + 2, nf - 1);
        const int f3 = min(f0 + 3, nf - 1);
        const int r0 = flist[f0], r1 = flist[f1], r2 = flist[f2], r3 = flist[f3];

        const float4* xp0 = (const float4*)(X + (size_t)r0 * D) + dg * 4;
        const float4* xp1 = (const float4*)(X + (size_t)r1 * D) + dg * 4;
        const float4* xp2 = (const float4*)(X + (size_t)r2 * D) + dg * 4;
        const float4* xp3 = (const float4*)(X + (size_t)r3 * D) + dg * 4;
        float4 xa0 = xp0[0], xa1 = xp0[1], xa2 = xp0[2], xa3 = xp0[3];
        float4 xb0 = xp1[0], xb1 = xp1[1], xb2 = xp1[2], xb3 = xp1[3];
        float4 xc0 = xp2[0], xc1 = xp2[1], xc2 = xp2[2], xc3 = xp2[3];
        float4 xd0 = xp3[0], xd1 = xp3[1], xd2 = xp3[2], xd3 = xp3[3];

        unsigned long long k0 = ~0ull, k1 = ~0ull, k2 = ~0ull, k3 = ~0ull;

#pragma unroll 2
        for (int it = 0; it < 64; ++it) {
            const int v = c * 1024 + it * 16 + e4;
            const float4* ep = (const float4*)(E + (size_t)v * D) + dg * 4;
            float4 b0 = ep[0], b1 = ep[1], b2 = ep[2], b3 = ep[3];
            float s0 = 0.0f, s1 = 0.0f, s2 = 0.0f, s3 = 0.0f;
            DOT16(s0, xa0, xa1, xa2, xa3, b0, b1, b2, b3)
            DOT16(s1, xb0, xb1, xb2, xb3, b0, b1, b2, b3)
            DOT16(s2, xc0, xc1, xc2, xc3, b0, b1, b2, b3)
            DOT16(s3, xd0, xd1, xd2, xd3, b0, b1, b2, b3)
            s0 += __shfl_xor(s0, 1, 64); s0 += __shfl_xor(s0, 2, 64);
            s1 += __shfl_xor(s1, 1, 64); s1 += __shfl_xor(s1, 2, 64);
            s2 += __shfl_xor(s2, 1, 64); s2 += __shfl_xor(s2, 2, 64);
            s3 += __shfl_xor(s3, 1, 64); s3 += __shfl_xor(s3, 2, 64);
            const float ev = e2[v];
            const unsigned long long vb = (unsigned long long)(unsigned)v;
            unsigned long long t;
            t = ((unsigned long long)enc32(fmaf(-2.0f, s0, ev)) << 32) | vb;
            k0 = t < k0 ? t : k0;
            t = ((unsigned long long)enc32(fmaf(-2.0f, s1, ev)) << 32) | vb;
            k1 = t < k1 ? t : k1;
            t = ((unsigned long long)enc32(fmaf(-2.0f, s2, ev)) << 32) | vb;
            k2 = t < k2 ? t : k2;
            t = ((unsigned long long)enc32(fmaf(-2.0f, s3, ev)) << 32) | vb;
            k3 = t < k3 ? t : k3;
        }

#pragma unroll
        for (int off = 4; off < 64; off <<= 1) {
            unsigned lo, hi;
            unsigned long long o;
            lo = __shfl_xor((unsigned)k0, off, 64); hi = __shfl_xor((unsigned)(k0 >> 32), off, 64);
            o = ((unsigned long long)hi << 32) | lo; k0 = o < k0 ? o : k0;
            lo = __shfl_xor((unsigned)k1, off, 64); hi = __shfl_xor((unsigned)(k1 >> 32), off, 64);
            o = ((unsigned long long)hi << 32) | lo; k1 = o < k1 ? o : k1;
            lo = __shfl_xor((unsigned)k2, off, 64); hi = __shfl_xor((unsigned)(k2 >> 32), off, 64);
            o = ((unsigned long long)hi << 32) | lo; k2 = o < k2 ? o : k2;
            lo = __shfl_xor((unsigned)k3, off, 64); hi = __shfl_xor((unsigned)(k3 >> 32), off, 64);
            o = ((unsigned long long)hi << 32) | lo; k3 = o < k3 ? o : k3;
        }

        if (lane == 0) {
            atomicMin(&packed[f0], k0);
            atomicMin(&packed[f1], k1);
            atomicMin(&packed[f2], k2);
            atomicMin(&packed[f3], k3);
        }
    }
}

// ---------------- kernel 5: gather + STE output + loss (grid-stride) --------
__global__ __launch_bounds__(256) void k_out(const float* __restrict__ X,
                                             const float* __restrict__ E,
                                             const unsigned* __restrict__ gidw,
                                             const unsigned long long* __restrict__ packed,
                                             float* __restrict__ dout) {
    float lsum = 0.0f;
    const int stride = gridDim.x * 256;
    for (int t = blockIdx.x * 256 + threadIdx.x; t < N * 16; t += stride) {
        const int n = t >> 4;
        const int d = (t & 15) * 4;
        const unsigned g = gidw[n];
        int idx;
        if (g & 1) {
            idx = (int)(unsigned)(packed[g >> 1] & 0xffffffffull);
            if (d == 0) dout[IDX_OFF + n] = (float)idx;
        } else {
            idx = (int)dout[IDX_OFF + n];
        }
        float4 x4 = *(const float4*)(X + (size_t)n * D + d);
        float4 q4 = *(const float4*)(E + (size_t)idx * D + d);
        float4 o;
        o.x = x4.x + (q4.x - x4.x);
        o.y = x4.y + (q4.y - x4.y);
        o.z = x4.z + (q4.z - x4.z);
        o.w = x4.w + (q4.w - x4.w);
        *(float4*)(dout + (size_t)n * D + d) = o;

        float dx = q4.x - x4.x, dy = q4.y - x4.y, dz = q4.z - x4.z,
              dw = q4.w - x4.w;
        lsum += dx * dx + dy * dy + dz * dz + dw * dw;
    }
#pragma unroll
    for (int off = 32; off; off >>= 1) lsum += __shfl_down(lsum, off, 64);
    __shared__ float ps[4];
    if ((threadIdx.x & 63) == 0) ps[threadIdx.x >> 6] = lsum;
    __syncthreads();
    if (threadIdx.x == 0) {
        float tot = ps[0] + ps[1] + ps[2] + ps[3];
        atomicAdd(dout + LOSS_OFF, tot * (1.25f / ((float)N * (float)D)));
    }
}

extern "C" void kernel_launch(void* const* d_in, const int* in_sizes, int n_in,
                              void* d_out, int out_size, void* d_ws,
                              size_t ws_size, hipStream_t stream) {
    const float* X = (const float*)d_in[0];
    const float* E = (const float*)d_in[1];
    float* out = (float*)d_out;

    char* ws = (char*)d_ws;
    _Float16* Ef16 = (_Float16*)ws;                                   // 1 MB
    float* e2 = (float*)(ws + 1048576);                               // 32 KB
    unsigned* gidw = (unsigned*)(ws + 1081344);                       // 256 KB
    int* fcount = (int*)(ws + 1343488);                               // 256 B
    int* flist = (int*)(ws + 1343744);                                // 256 KB
    unsigned long long* packed = (unsigned long long*)(ws + 1605888); // 512 KB
    float4* part4 = (float4*)(ws + 2130176);                          // 2 MB

    k_split<<<V / 256, 256, 0, stream>>>(E, Ef16, e2, out, fcount);
    k_argmin<<<(N / 128) * 2, 256, 0, stream>>>(X, Ef16, e2, part4);
    k_group<<<N / 4, 256, 0, stream>>>(X, E, e2, part4, gidw, fcount, flist, packed, out);
    k_full<<<1024, 256, 0, stream>>>(X, E, e2, fcount, flist, packed);
    k_out<<<512, 256, 0, stream>>>(X, E, gidw, packed, out);
}

// Round 8
// 199.776 us; speedup vs baseline: 1.2759x; 1.0547x over previous
//
#include <hip/hip_runtime.h>

#define N 65536
#define D 64
#define V 8192
#define LOSS_OFF (N * D)
#define IDX_OFF (N * D + 1)
#define MARGIN 0.02f
#define NPART 4

typedef _Float16 half8 __attribute__((ext_vector_type(8)));
typedef float f32x4 __attribute__((ext_vector_type(4)));

typedef __attribute__((address_space(1))) const void gas_t;
typedef __attribute__((address_space(3))) void las_t;

// 16-dim partial dot with named float4 regs (never an indexed array -> no scratch)
#define DOT16(s, A0, A1, A2, A3, B0, B1, B2, B3)                         \
    s = fmaf(A0.x, B0.x, s); s = fmaf(A0.y, B0.y, s);                    \
    s = fmaf(A0.z, B0.z, s); s = fmaf(A0.w, B0.w, s);                    \
    s = fmaf(A1.x, B1.x, s); s = fmaf(A1.y, B1.y, s);                    \
    s = fmaf(A1.z, B1.z, s); s = fmaf(A1.w, B1.w, s);                    \
    s = fmaf(A2.x, B2.x, s); s = fmaf(A2.y, B2.y, s);                    \
    s = fmaf(A2.z, B2.z, s); s = fmaf(A2.w, B2.w, s);                    \
    s = fmaf(A3.x, B3.x, s); s = fmaf(A3.y, B3.y, s);                    \
    s = fmaf(A3.z, B3.z, s); s = fmaf(A3.w, B3.w, s);

// order-preserving f32 -> u32 (finite values): min score == min encoding
__device__ __forceinline__ unsigned enc32(float f) {
    unsigned u = __float_as_uint(f);
    return (u & 0x80000000u) ? ~u : (u | 0x80000000u);
}

// ---------------- kernel 1: Ef16 = f16(-2E), e2 = sum E^2 (8 thr/row) -------
__global__ __launch_bounds__(256) void k_split(const float* __restrict__ E,
                                               _Float16* __restrict__ Ef16,
                                               float* __restrict__ e2,
                                               float* __restrict__ dout,
                                               int* __restrict__ fcount) {
    const int t = blockIdx.x * 256 + threadIdx.x;  // 65536 threads
    if (t == 0) {
        dout[LOSS_OFF] = 0.0f;
        *fcount = 0;
    }
    const int row = t >> 3;
    const int seg = t & 7;  // 8 dims per thread
    const float4* p = (const float4*)(E + (size_t)row * D + seg * 8);
    float4 a = p[0], b = p[1];
    float s = a.x * a.x + a.y * a.y + a.z * a.z + a.w * a.w +
              b.x * b.x + b.y * b.y + b.z * b.z + b.w * b.w;
    s += __shfl_xor(s, 1, 8);
    s += __shfl_xor(s, 2, 8);
    s += __shfl_xor(s, 4, 8);
    if (seg == 0) e2[row] = s;
    half8 h;
    h[0] = (_Float16)(-2.0f * a.x); h[1] = (_Float16)(-2.0f * a.y);
    h[2] = (_Float16)(-2.0f * a.z); h[3] = (_Float16)(-2.0f * a.w);
    h[4] = (_Float16)(-2.0f * b.x); h[5] = (_Float16)(-2.0f * b.y);
    h[6] = (_Float16)(-2.0f * b.z); h[7] = (_Float16)(-2.0f * b.w);
    *(half8*)(Ef16 + (size_t)row * D + seg * 8) = h;
}

// ---------------- kernel 2: MFMA approx argmin, V-split x4, 8 waves ---------
// grid = (N/256) x 4 partitions (bid&3), 512 thr = 8 waves; wave owns 32 rows.
// A = E-tile (16 entries), B = X rows. acc f32x4 = 4 consecutive entries of
// one x-row; exact-f32 e2 quad (global dwordx4, L2-hit) is the MFMA C-init.
// Leaf = 32 entries (ch,kg); one MERGE per chunk -> {m1,m2,gid} per row/part.
#define MERGE(M1, M2, GID, L, PID)          \
    {                                       \
        bool bt = (L) < (M1);               \
        float m2c = bt ? (M1) : (L);        \
        (M2) = fminf((M2), m2c);            \
        (GID) = bt ? (PID) : (GID);         \
        (M1) = fminf((M1), (L));            \
    }

__global__ __launch_bounds__(512) void k_argmin(const float* __restrict__ X,
                                                const _Float16* __restrict__ Ef16,
                                                const float* __restrict__ e2,
                                                float4* __restrict__ part4) {
    __shared__ __align__(16) _Float16 els[2][8192];  // exactly 32 KB

    const int tid = threadIdx.x;
    const int lane = tid & 63;
    const int wave = tid >> 6;             // 0..7
    const int P = blockIdx.x & 3;          // V-partition
    const int rb = blockIdx.x >> 2;
    const int c4 = lane & 15;
    const int kg = lane >> 4;              // 0..3
    const int wrow = rb * 256 + wave * 32;
    const int sw = c4 & 7;
    const int k0off = (kg ^ sw) * 8;
    const int k1off = ((4 + kg) ^ sw) * 8;
    const int ch0 = P * 16;

    // B-frags: X rows (loop-invariant registers)
    half8 x00, x01, x10, x11;
    {
        const float* xr0 = X + (size_t)(wrow + c4) * D;
        const float* xr1 = X + (size_t)(wrow + 16 + c4) * D;
#pragma unroll
        for (int f = 0; f < 2; ++f) {
            float4 lo = *(const float4*)(xr0 + f * 32 + kg * 8);
            float4 hi = *(const float4*)(xr0 + f * 32 + kg * 8 + 4);
            half8 h;
            h[0] = (_Float16)lo.x; h[1] = (_Float16)lo.y;
            h[2] = (_Float16)lo.z; h[3] = (_Float16)lo.w;
            h[4] = (_Float16)hi.x; h[5] = (_Float16)hi.y;
            h[6] = (_Float16)hi.z; h[7] = (_Float16)hi.w;
            if (f == 0) x00 = h; else x01 = h;
        }
#pragma unroll
        for (int f = 0; f < 2; ++f) {
            float4 lo = *(const float4*)(xr1 + f * 32 + kg * 8);
            float4 hi = *(const float4*)(xr1 + f * 32 + kg * 8 + 4);
            half8 h;
            h[0] = (_Float16)lo.x; h[1] = (_Float16)lo.y;
            h[2] = (_Float16)lo.z; h[3] = (_Float16)lo.w;
            h[4] = (_Float16)hi.x; h[5] = (_Float16)hi.y;
            h[6] = (_Float16)hi.z; h[7] = (_Float16)hi.w;
            if (f == 0) x10 = h; else x11 = h;
        }
    }

    // staging: 2 named per-thread global pointers (512 thr x 2 x 16B = 16KB),
    // fixed LDS offsets; swizzle math hoisted. src advances 8192 halves/chunk.
    const int q0 = tid, q1 = tid + 512;
    const _Float16* gs0 = Ef16 + (size_t)(ch0 * 128 + (q0 >> 3)) * 64 + ((q0 & 7) ^ ((q0 >> 3) & 7)) * 8;
    const _Float16* gs1 = Ef16 + (size_t)(ch0 * 128 + (q1 >> 3)) * 64 + ((q1 & 7) ^ ((q1 >> 3) & 7)) * 8;
    const int ld0 = q0 * 8, ld1 = q1 * 8;

#define STAGE(BUF)                                                            \
    {                                                                         \
        __builtin_amdgcn_global_load_lds((gas_t*)gs0, (las_t*)&els[BUF][ld0], 16, 0, 0); \
        __builtin_amdgcn_global_load_lds((gas_t*)gs1, (las_t*)&els[BUF][ld1], 16, 0, 0); \
        gs0 += 8192; gs1 += 8192;                                             \
    }

    float m1a = 3.4e38f, m2a = 3.4e38f, m1b = 3.4e38f, m2b = 3.4e38f;
    unsigned gida = 0, gidb = 0;
    const unsigned kgu = (unsigned)kg;

    // sequential fmin chains -> v_min3 fusion
#define TSTEP(T, E2Q)                                                         \
    {                                                                         \
        const half8 a0 = *(const half8*)&els[buf][(T * 16 + c4) * 64 + k0off];\
        const half8 a1 = *(const half8*)&els[buf][(T * 16 + c4) * 64 + k1off];\
        f32x4 acc0 = __builtin_amdgcn_mfma_f32_16x16x32_f16(a0, x00, E2Q, 0, 0, 0); \
        acc0 = __builtin_amdgcn_mfma_f32_16x16x32_f16(a1, x01, acc0, 0, 0, 0);\
        f32x4 acc1 = __builtin_amdgcn_mfma_f32_16x16x32_f16(a0, x10, E2Q, 0, 0, 0); \
        acc1 = __builtin_amdgcn_mfma_f32_16x16x32_f16(a1, x11, acc1, 0, 0, 0);\
        La = fminf(fminf(fminf(fminf(La, acc0[0]), acc0[1]), acc0[2]), acc0[3]); \
        Lb = fminf(fminf(fminf(fminf(Lb, acc1[0]), acc1[1]), acc1[2]), acc1[3]); \
    }

    STAGE(0)
    const f32x4* e2p = (const f32x4*)(e2 + (size_t)ch0 * 128) + kg;

    for (int ci = 0; ci < 16; ++ci) {
        __syncthreads();  // drains prior STAGE (vmcnt0) + protects buf reuse
        // e2 quads FIRST (FIFO vmcnt: their wait must not drain next STAGE)
        const f32x4 e2q0 = e2p[0],  e2q1 = e2p[4],  e2q2 = e2p[8],  e2q3 = e2p[12];
        const f32x4 e2q4 = e2p[16], e2q5 = e2p[20], e2q6 = e2p[24], e2q7 = e2p[28];
        e2p += 32;
        if (ci < 15) STAGE((ci + 1) & 1)
        const int buf = ci & 1;

        float La = 3.4e38f, Lb = 3.4e38f;
        TSTEP(0, e2q0) TSTEP(1, e2q1) TSTEP(2, e2q2) TSTEP(3, e2q3)
        TSTEP(4, e2q4) TSTEP(5, e2q5) TSTEP(6, e2q6) TSTEP(7, e2q7)

        // leaf = 32 entries {ch*128 + t*16 + kg*4 + j}
        unsigned pid = (unsigned)((ch0 + ci) * 4) + kgu;
        MERGE(m1a, m2a, gida, La, pid)
        MERGE(m1b, m2b, gidb, Lb, pid)
    }

    // merge the 4 kg lane-groups (lanes l, l+16, l+32, l+48 share an x-row)
#pragma unroll
    for (int off = 16; off < 64; off <<= 1) {
        float o1, o2;
        unsigned og;
        o1 = __shfl_xor(m1a, off, 64); o2 = __shfl_xor(m2a, off, 64);
        og = (unsigned)__shfl_xor((int)gida, off, 64);
        m2a = fminf(fminf(fmaxf(m1a, o1), m2a), o2);
        if (o1 < m1a) gida = og;
        m1a = fminf(m1a, o1);
        o1 = __shfl_xor(m1b, off, 64); o2 = __shfl_xor(m2b, off, 64);
        og = (unsigned)__shfl_xor((int)gidb, off, 64);
        m2b = fminf(fminf(fmaxf(m1b, o1), m2b), o2);
        if (o1 < m1b) gidb = og;
        m1b = fminf(m1b, o1);
    }

    if (lane < 16) {
        float4 r;
        r.x = m1a; r.y = m2a; r.z = __uint_as_float(gida); r.w = 0.0f;
        part4[(size_t)P * N + wrow + lane] = r;
        r.x = m1b; r.y = m2b; r.z = __uint_as_float(gidb);
        part4[(size_t)P * N + wrow + 16 + lane] = r;
    }
}

// ---------------- kernel 3: merge 4 partitions + full unflagged epilogue ----
// one wave per row: top-2 merge; unflagged -> exact leaf rescan + idx + STE
// output + loss partial (lpart[bid], no atomic). flagged -> compact to flist.
__global__ __launch_bounds__(256) void k_group(const float* __restrict__ X,
                                               const float* __restrict__ E,
                                               const float* __restrict__ e2,
                                               const float4* __restrict__ part4,
                                               int* __restrict__ fcount,
                                               int* __restrict__ flist,
                                               unsigned long long* __restrict__ packed,
                                               float* __restrict__ lpart,
                                               float* __restrict__ dout) {
    const int lane = threadIdx.x & 63;
    const int wave = threadIdx.x >> 6;
    const int row = blockIdx.x * 4 + wave;

    float m1, m2;
    unsigned g;
    {
        const float4 r0 = part4[row];
        m1 = r0.x; m2 = r0.y; g = __float_as_uint(r0.z);
#pragma unroll
        for (int k = 1; k < NPART; ++k) {
            const float4 r = part4[(size_t)k * N + row];
            const unsigned rg = __float_as_uint(r.z);
            if (r.x < m1) {
                m2 = fminf(m2, m1);
                m1 = r.x;
                g = rg;
            } else {
                m2 = fminf(m2, r.x);
            }
            m2 = fminf(m2, r.y);
        }
    }

    float lossp = 0.0f;
    if (m2 - m1 < MARGIN) {  // conservative: ties & close calls -> exact scan
        if (lane == 0) {
            int p = atomicAdd(fcount, 1);
            flist[p] = row;
            packed[p] = ~0ull;
        }
    } else {
        // exact f32 rescan of winning 32-entry leaf:
        // v = ch*128 + (s>>2)*16 + kg*4 + (s&3), s strictly increasing
        const int ch = (int)(g >> 2);
        const int kgr = (int)(g & 3);
        const int e4 = lane >> 2;
        const int dg = lane & 3;
        const float4* xp = (const float4*)(X + (size_t)row * D) + dg * 4;
        float4 xa0 = xp[0], xa1 = xp[1], xa2 = xp[2], xa3 = xp[3];

        float best = 3.4e38f;
        int bidx = 0x7fffffff;
#pragma unroll
        for (int it = 0; it < 2; ++it) {
            const int s = it * 16 + e4;
            const int v = ch * 128 + ((s >> 2) << 4) + kgr * 4 + (s & 3);
            const float4* ep = (const float4*)(E + (size_t)v * D) + dg * 4;
            float4 b0 = ep[0], b1 = ep[1], b2 = ep[2], b3 = ep[3];
            float s0 = 0.0f;
            DOT16(s0, xa0, xa1, xa2, xa3, b0, b1, b2, b3)
            s0 += __shfl_xor(s0, 1, 64);
            s0 += __shfl_xor(s0, 2, 64);
            float d = fmaf(-2.0f, s0, e2[v]);
            if (d < best) { best = d; bidx = v; }
        }
#pragma unroll
        for (int off = 4; off < 64; off <<= 1) {
            float ob = __shfl_xor(best, off, 64);
            int oi = __shfl_xor(bidx, off, 64);
            if (ob < best || (ob == best && oi < bidx)) { best = ob; bidx = oi; }
        }
        if (lane == 0) dout[IDX_OFF + row] = (float)bidx;
        // STE output + loss partial (16 lanes x float4)
        if (lane < 16) {
            float4 x4 = *(const float4*)(X + (size_t)row * D + lane * 4);
            float4 q4 = *(const float4*)(E + (size_t)bidx * D + lane * 4);
            float4 o;
            o.x = x4.x + (q4.x - x4.x);
            o.y = x4.y + (q4.y - x4.y);
            o.z = x4.z + (q4.z - x4.z);
            o.w = x4.w + (q4.w - x4.w);
            *(float4*)(dout + (size_t)row * D + lane * 4) = o;
            float dx = q4.x - x4.x, dy = q4.y - x4.y, dz = q4.z - x4.z,
                  dw = q4.w - x4.w;
            lossp = dx * dx + dy * dy + dz * dz + dw * dw;
        }
    }

    // block loss partial -> lpart[bid] (plain store; summed in k_out2)
#pragma unroll
    for (int off = 32; off; off >>= 1) lossp += __shfl_down(lossp, off, 64);
    __shared__ float ps[4];
    if (lane == 0) ps[wave] = lossp;
    __syncthreads();
    if (threadIdx.x == 0) lpart[blockIdx.x] = ps[0] + ps[1] + ps[2] + ps[3];
}

// ---------------- kernel 4: exact full scan for FLAGGED rows ----------------
// work item = (row-quad, 1/8 chunk of V); grid-stride; atomicMin u64 merge.
__global__ __launch_bounds__(256) void k_full(const float* __restrict__ X,
                                              const float* __restrict__ E,
                                              const float* __restrict__ e2,
                                              const int* __restrict__ fcount,
                                              const int* __restrict__ flist,
                                              unsigned long long* __restrict__ packed) {
    const int nf = *fcount;
    if (nf == 0) return;
    const int nq = (nf + 3) >> 2;
    const int total = nq * 8;
    const int lane = threadIdx.x & 63;
    const int nwaves = gridDim.x * 4;
    int item = blockIdx.x * 4 + (threadIdx.x >> 6);
    const int e4 = lane >> 2;
    const int dg = lane & 3;

    for (; item < total; item += nwaves) {
        const int qi = item >> 3;
        const int c = item & 7;
        const int f0 = qi * 4;
        const int f1 = min(f0 + 1, nf - 1);
        const int f2 = min(f0 + 2, nf - 1);
        const int f3 = min(f0 + 3, nf - 1);
        const int r0 = flist[f0], r1 = flist[f1], r2 = flist[f2], r3 = flist[f3];

        const float4* xp0 = (const float4*)(X + (size_t)r0 * D) + dg * 4;
        const float4* xp1 = (const float4*)(X + (size_t)r1 * D) + dg * 4;
        const float4* xp2 = (const float4*)(X + (size_t)r2 * D) + dg * 4;
        const float4* xp3 = (const float4*)(X + (size_t)r3 * D) + dg * 4;
        float4 xa0 = xp0[0], xa1 = xp0[1], xa2 = xp0[2], xa3 = xp0[3];
        float4 xb0 = xp1[0], xb1 = xp1[1], xb2 = xp1[2], xb3 = xp1[3];
        float4 xc0 = xp2[0], xc1 = xp2[1], xc2 = xp2[2], xc3 = xp2[3];
        float4 xd0 = xp3[0], xd1 = xp3[1], xd2 = xp3[2], xd3 = xp3[3];

        unsigned long long k0 = ~0ull, k1 = ~0ull, k2 = ~0ull, k3 = ~0ull;

#pragma unroll 2
        for (int it = 0; it < 64; ++it) {
            const int v = c * 1024 + it * 16 + e4;
            const float4* ep = (const float4*)(E + (size_t)v * D) + dg * 4;
            float4 b0 = ep[0], b1 = ep[1], b2 = ep[2], b3 = ep[3];
            float s0 = 0.0f, s1 = 0.0f, s2 = 0.0f, s3 = 0.0f;
            DOT16(s0, xa0, xa1, xa2, xa3, b0, b1, b2, b3)
            DOT16(s1, xb0, xb1, xb2, xb3, b0, b1, b2, b3)
            DOT16(s2, xc0, xc1, xc2, xc3, b0, b1, b2, b3)
            DOT16(s3, xd0, xd1, xd2, xd3, b0, b1, b2, b3)
            s0 += __shfl_xor(s0, 1, 64); s0 += __shfl_xor(s0, 2, 64);
            s1 += __shfl_xor(s1, 1, 64); s1 += __shfl_xor(s1, 2, 64);
            s2 += __shfl_xor(s2, 1, 64); s2 += __shfl_xor(s2, 2, 64);
            s3 += __shfl_xor(s3, 1, 64); s3 += __shfl_xor(s3, 2, 64);
            const float ev = e2[v];
            const unsigned long long vb = (unsigned long long)(unsigned)v;
            unsigned long long t;
            t = ((unsigned long long)enc32(fmaf(-2.0f, s0, ev)) << 32) | vb;
            k0 = t < k0 ? t : k0;
            t = ((unsigned long long)enc32(fmaf(-2.0f, s1, ev)) << 32) | vb;
            k1 = t < k1 ? t : k1;
            t = ((unsigned long long)enc32(fmaf(-2.0f, s2, ev)) << 32) | vb;
            k2 = t < k2 ? t : k2;
            t = ((unsigned long long)enc32(fmaf(-2.0f, s3, ev)) << 32) | vb;
            k3 = t < k3 ? t : k3;
        }

#pragma unroll
        for (int off = 4; off < 64; off <<= 1) {
            unsigned lo, hi;
            unsigned long long o;
            lo = __shfl_xor((unsigned)k0, off, 64); hi = __shfl_xor((unsigned)(k0 >> 32), off, 64);
            o = ((unsigned long long)hi << 32) | lo; k0 = o < k0 ? o : k0;
            lo = __shfl_xor((unsigned)k1, off, 64); hi = __shfl_xor((unsigned)(k1 >> 32), off, 64);
            o = ((unsigned long long)hi << 32) | lo; k1 = o < k1 ? o : k1;
            lo = __shfl_xor((unsigned)k2, off, 64); hi = __shfl_xor((unsigned)(k2 >> 32), off, 64);
            o = ((unsigned long long)hi << 32) | lo; k2 = o < k2 ? o : k2;
            lo = __shfl_xor((unsigned)k3, off, 64); hi = __shfl_xor((unsigned)(k3 >> 32), off, 64);
            o = ((unsigned long long)hi << 32) | lo; k3 = o < k3 ? o : k3;
        }

        if (lane == 0) {
            atomicMin(&packed[f0], k0);
            atomicMin(&packed[f1], k1);
            atomicMin(&packed[f2], k2);
            atomicMin(&packed[f3], k3);
        }
    }
}

// ---------------- kernel 5: flagged-row epilogue + loss finalize ------------
// 256 blocks. block b: wave0 folds lpart[b*64..+63]; grid-stride waves handle
// flagged rows (idx + STE + loss); one atomicAdd per block.
__global__ __launch_bounds__(256) void k_out2(const float* __restrict__ X,
                                              const float* __restrict__ E,
                                              const int* __restrict__ fcount,
                                              const int* __restrict__ flist,
                                              const unsigned long long* __restrict__ packed,
                                              const float* __restrict__ lpart,
                                              float* __restrict__ dout) {
    const int lane = threadIdx.x & 63;
    const int wave = threadIdx.x >> 6;
    float lossp = 0.0f;
    if (wave == 0) lossp += lpart[blockIdx.x * 64 + lane];

    const int nf = *fcount;
    const int nwaves = gridDim.x * 4;
    for (int i = blockIdx.x * 4 + wave; i < nf; i += nwaves) {
        const int row = flist[i];
        const int idx = (int)(unsigned)(packed[i] & 0xffffffffull);
        if (lane == 0) dout[IDX_OFF + row] = (float)idx;
        if (lane < 16) {
            float4 x4 = *(const float4*)(X + (size_t)row * D + lane * 4);
            float4 q4 = *(const float4*)(E + (size_t)idx * D + lane * 4);
            float4 o;
            o.x = x4.x + (q4.x - x4.x);
            o.y = x4.y + (q4.y - x4.y);
            o.z = x4.z + (q4.z - x4.z);
            o.w = x4.w + (q4.w - x4.w);
            *(float4*)(dout + (size_t)row * D + lane * 4) = o;
            float dx = q4.x - x4.x, dy = q4.y - x4.y, dz = q4.z - x4.z,
                  dw = q4.w - x4.w;
            lossp += dx * dx + dy * dy + dz * dz + dw * dw;
        }
    }

#pragma unroll
    for (int off = 32; off; off >>= 1) lossp += __shfl_down(lossp, off, 64);
    __shared__ float ps[4];
    if (lane == 0) ps[wave] = lossp;
    __syncthreads();
    if (threadIdx.x == 0) {
        float tot = ps[0] + ps[1] + ps[2] + ps[3];
        atomicAdd(dout + LOSS_OFF, tot * (1.25f / ((float)N * (float)D)));
    }
}

extern "C" void kernel_launch(void* const* d_in, const int* in_sizes, int n_in,
                              void* d_out, int out_size, void* d_ws,
                              size_t ws_size, hipStream_t stream) {
    const float* X = (const float*)d_in[0];
    const float* E = (const float*)d_in[1];
    float* out = (float*)d_out;

    char* ws = (char*)d_ws;
    _Float16* Ef16 = (_Float16*)ws;                                   // 1 MB
    float* e2 = (float*)(ws + 1048576);                               // 32 KB
    int* fcount = (int*)(ws + 1081344);                               // 256 B
    int* flist = (int*)(ws + 1081600);                                // 256 KB
    unsigned long long* packed = (unsigned long long*)(ws + 1343744); // 512 KB
    float* lpart = (float*)(ws + 1868032);                            // 64 KB
    float4* part4 = (float4*)(ws + 1933568);                          // 4 MB

    k_split<<<256, 256, 0, stream>>>(E, Ef16, e2, out, fcount);
    k_argmin<<<(N / 256) * NPART, 512, 0, stream>>>(X, Ef16, e2, part4);
    k_group<<<N / 4, 256, 0, stream>>>(X, E, e2, part4, fcount, flist, packed, lpart, out);
    k_full<<<1024, 256, 0, stream>>>(X, E, e2, fcount, flist, packed);
    k_out2<<<256, 256, 0, stream>>>(X, E, fcount, flist, packed, lpart, out);
}

// Round 9
// 174.817 us; speedup vs baseline: 1.4581x; 1.1428x over previous
//
#include <hip/hip_runtime.h>

#define N 65536
#define D 64
#define V 8192
#define LOSS_OFF (N * D)
#define IDX_OFF (N * D + 1)
#define MARGIN 0.02f
#define NPART 4

typedef _Float16 half8 __attribute__((ext_vector_type(8)));
typedef float f32x4 __attribute__((ext_vector_type(4)));

typedef __attribute__((address_space(1))) const void gas_t;
typedef __attribute__((address_space(3))) void las_t;

// 16-dim partial dot with named float4 regs (never an indexed array -> no scratch)
#define DOT16(s, A0, A1, A2, A3, B0, B1, B2, B3)                         \
    s = fmaf(A0.x, B0.x, s); s = fmaf(A0.y, B0.y, s);                    \
    s = fmaf(A0.z, B0.z, s); s = fmaf(A0.w, B0.w, s);                    \
    s = fmaf(A1.x, B1.x, s); s = fmaf(A1.y, B1.y, s);                    \
    s = fmaf(A1.z, B1.z, s); s = fmaf(A1.w, B1.w, s);                    \
    s = fmaf(A2.x, B2.x, s); s = fmaf(A2.y, B2.y, s);                    \
    s = fmaf(A2.z, B2.z, s); s = fmaf(A2.w, B2.w, s);                    \
    s = fmaf(A3.x, B3.x, s); s = fmaf(A3.y, B3.y, s);                    \
    s = fmaf(A3.z, B3.z, s); s = fmaf(A3.w, B3.w, s);

// order-preserving f32 -> u32 (finite values): min score == min encoding
__device__ __forceinline__ unsigned enc32(float f) {
    unsigned u = __float_as_uint(f);
    return (u & 0x80000000u) ? ~u : (u | 0x80000000u);
}

// ---------------- kernel 1: Ef16 = f16(-2E), e2 = sum E^2 (8 thr/row) -------
__global__ __launch_bounds__(256) void k_split(const float* __restrict__ E,
                                               _Float16* __restrict__ Ef16,
                                               float* __restrict__ e2,
                                               float* __restrict__ dout,
                                               int* __restrict__ fcount) {
    const int t = blockIdx.x * 256 + threadIdx.x;  // 65536 threads
    if (t == 0) {
        dout[LOSS_OFF] = 0.0f;
        *fcount = 0;
    }
    const int row = t >> 3;
    const int seg = t & 7;  // 8 dims per thread
    const float4* p = (const float4*)(E + (size_t)row * D + seg * 8);
    float4 a = p[0], b = p[1];
    float s = a.x * a.x + a.y * a.y + a.z * a.z + a.w * a.w +
              b.x * b.x + b.y * b.y + b.z * b.z + b.w * b.w;
    s += __shfl_xor(s, 1, 8);
    s += __shfl_xor(s, 2, 8);
    s += __shfl_xor(s, 4, 8);
    if (seg == 0) e2[row] = s;
    half8 h;
    h[0] = (_Float16)(-2.0f * a.x); h[1] = (_Float16)(-2.0f * a.y);
    h[2] = (_Float16)(-2.0f * a.z); h[3] = (_Float16)(-2.0f * a.w);
    h[4] = (_Float16)(-2.0f * b.x); h[5] = (_Float16)(-2.0f * b.y);
    h[6] = (_Float16)(-2.0f * b.z); h[7] = (_Float16)(-2.0f * b.w);
    *(half8*)(Ef16 + (size_t)row * D + seg * 8) = h;
}

// ---------------- kernel 2: MFMA approx argmin, V-split x4, quad leaves -----
// grid = (N/256) x 4 partitions (bid&3), 512 thr = 8 waves; wave owns 32 rows.
// A = E-tile (16 entries), B = X rows. acc f32x4 = 4 CONSECUTIVE entries of
// one x-row (one quad); exact-f32 e2 quad is the MFMA C-init. Leaf = quad
// (4 entries); MERGE per acc -> {m1, m2, quad-id} per row/partition.
#define MERGE(M1, M2, GID, L, PID)          \
    {                                       \
        bool bt = (L) < (M1);               \
        float m2c = bt ? (M1) : (L);        \
        (M2) = fminf((M2), m2c);            \
        (GID) = bt ? (PID) : (GID);         \
        (M1) = fminf((M1), (L));            \
    }

__global__ __launch_bounds__(512) void k_argmin(const float* __restrict__ X,
                                                const _Float16* __restrict__ Ef16,
                                                const float* __restrict__ e2,
                                                float4* __restrict__ part4) {
    __shared__ __align__(16) _Float16 els[2][8192];  // exactly 32 KB

    const int tid = threadIdx.x;
    const int lane = tid & 63;
    const int wave = tid >> 6;             // 0..7
    const int P = blockIdx.x & 3;          // V-partition
    const int rb = blockIdx.x >> 2;
    const int c4 = lane & 15;
    const int kg = lane >> 4;              // 0..3
    const int wrow = rb * 256 + wave * 32;
    const int sw = c4 & 7;
    const int k0off = (kg ^ sw) * 8;
    const int k1off = ((4 + kg) ^ sw) * 8;
    const int ch0 = P * 16;

    // B-frags: X rows (loop-invariant registers)
    half8 x00, x01, x10, x11;
    {
        const float* xr0 = X + (size_t)(wrow + c4) * D;
        const float* xr1 = X + (size_t)(wrow + 16 + c4) * D;
#pragma unroll
        for (int f = 0; f < 2; ++f) {
            float4 lo = *(const float4*)(xr0 + f * 32 + kg * 8);
            float4 hi = *(const float4*)(xr0 + f * 32 + kg * 8 + 4);
            half8 h;
            h[0] = (_Float16)lo.x; h[1] = (_Float16)lo.y;
            h[2] = (_Float16)lo.z; h[3] = (_Float16)lo.w;
            h[4] = (_Float16)hi.x; h[5] = (_Float16)hi.y;
            h[6] = (_Float16)hi.z; h[7] = (_Float16)hi.w;
            if (f == 0) x00 = h; else x01 = h;
        }
#pragma unroll
        for (int f = 0; f < 2; ++f) {
            float4 lo = *(const float4*)(xr1 + f * 32 + kg * 8);
            float4 hi = *(const float4*)(xr1 + f * 32 + kg * 8 + 4);
            half8 h;
            h[0] = (_Float16)lo.x; h[1] = (_Float16)lo.y;
            h[2] = (_Float16)lo.z; h[3] = (_Float16)lo.w;
            h[4] = (_Float16)hi.x; h[5] = (_Float16)hi.y;
            h[6] = (_Float16)hi.z; h[7] = (_Float16)hi.w;
            if (f == 0) x10 = h; else x11 = h;
        }
    }

    // staging: 2 named per-thread global pointers (512 thr x 2 x 16B = 16KB),
    // fixed LDS offsets; swizzle math hoisted. src advances 8192 halves/chunk.
    const int q0 = tid, q1 = tid + 512;
    const _Float16* gs0 = Ef16 + (size_t)(ch0 * 128 + (q0 >> 3)) * 64 + ((q0 & 7) ^ ((q0 >> 3) & 7)) * 8;
    const _Float16* gs1 = Ef16 + (size_t)(ch0 * 128 + (q1 >> 3)) * 64 + ((q1 & 7) ^ ((q1 >> 3) & 7)) * 8;
    const int ld0 = q0 * 8, ld1 = q1 * 8;

#define STAGE(BUF)                                                            \
    {                                                                         \
        __builtin_amdgcn_global_load_lds((gas_t*)gs0, (las_t*)&els[BUF][ld0], 16, 0, 0); \
        __builtin_amdgcn_global_load_lds((gas_t*)gs1, (las_t*)&els[BUF][ld1], 16, 0, 0); \
        gs0 += 8192; gs1 += 8192;                                             \
    }

    float m1a = 3.4e38f, m2a = 3.4e38f, m1b = 3.4e38f, m2b = 3.4e38f;
    unsigned gida = 0, gidb = 0;

    // quad id of acc at TSTEP t: (ch*128 + t*16 + kg*4) >> 2 = ch*32 + t*4 + kg
#define TSTEP(T, E2Q)                                                         \
    {                                                                         \
        const half8 a0 = *(const half8*)&els[buf][(T * 16 + c4) * 64 + k0off];\
        const half8 a1 = *(const half8*)&els[buf][(T * 16 + c4) * 64 + k1off];\
        f32x4 acc0 = __builtin_amdgcn_mfma_f32_16x16x32_f16(a0, x00, E2Q, 0, 0, 0); \
        acc0 = __builtin_amdgcn_mfma_f32_16x16x32_f16(a1, x01, acc0, 0, 0, 0);\
        f32x4 acc1 = __builtin_amdgcn_mfma_f32_16x16x32_f16(a0, x10, E2Q, 0, 0, 0); \
        acc1 = __builtin_amdgcn_mfma_f32_16x16x32_f16(a1, x11, acc1, 0, 0, 0);\
        float Lq0 = fminf(fminf(acc0[0], acc0[1]), fminf(acc0[2], acc0[3]));  \
        float Lq1 = fminf(fminf(acc1[0], acc1[1]), fminf(acc1[2], acc1[3]));  \
        const unsigned pid = pidq + T * 4;                                    \
        MERGE(m1a, m2a, gida, Lq0, pid)                                       \
        MERGE(m1b, m2b, gidb, Lq1, pid)                                       \
    }

    STAGE(0)
    const f32x4* e2p = (const f32x4*)(e2 + (size_t)ch0 * 128) + kg;
    unsigned pidq = (unsigned)(ch0 * 32 + kg);

    for (int ci = 0; ci < 16; ++ci) {
        __syncthreads();  // drains prior STAGE (vmcnt0) + protects buf reuse
        // e2 quads FIRST (FIFO vmcnt: their wait must not drain next STAGE)
        const f32x4 e2q0 = e2p[0],  e2q1 = e2p[4],  e2q2 = e2p[8],  e2q3 = e2p[12];
        const f32x4 e2q4 = e2p[16], e2q5 = e2p[20], e2q6 = e2p[24], e2q7 = e2p[28];
        e2p += 32;
        if (ci < 15) STAGE((ci + 1) & 1)
        const int buf = ci & 1;

        TSTEP(0, e2q0) TSTEP(1, e2q1) TSTEP(2, e2q2) TSTEP(3, e2q3)
        TSTEP(4, e2q4) TSTEP(5, e2q5) TSTEP(6, e2q6) TSTEP(7, e2q7)
        pidq += 32;
    }

    // merge the 4 kg lane-groups (lanes l, l+16, l+32, l+48 share an x-row)
#pragma unroll
    for (int off = 16; off < 64; off <<= 1) {
        float o1, o2;
        unsigned og;
        o1 = __shfl_xor(m1a, off, 64); o2 = __shfl_xor(m2a, off, 64);
        og = (unsigned)__shfl_xor((int)gida, off, 64);
        m2a = fminf(fminf(fmaxf(m1a, o1), m2a), o2);
        if (o1 < m1a) gida = og;
        m1a = fminf(m1a, o1);
        o1 = __shfl_xor(m1b, off, 64); o2 = __shfl_xor(m2b, off, 64);
        og = (unsigned)__shfl_xor((int)gidb, off, 64);
        m2b = fminf(fminf(fmaxf(m1b, o1), m2b), o2);
        if (o1 < m1b) gidb = og;
        m1b = fminf(m1b, o1);
    }

    if (lane < 16) {
        float4 r;
        r.x = m1a; r.y = m2a; r.z = __uint_as_float(gida); r.w = 0.0f;
        part4[(size_t)P * N + wrow + lane] = r;
        r.x = m1b; r.y = m2b; r.z = __uint_as_float(gidb);
        part4[(size_t)P * N + wrow + 16 + lane] = r;
    }
}

// ---------------- kernel 3: merge partitions + exact 4-entry quad rescan ----
// 4 rows per wave (16 lanes each): partition top-2 merge (redundant per lane);
// unflagged -> exact f32 rescan of the 4 consecutive winning entries + idx +
// STE output + loss partial; flagged -> compact to flist for k_full.
__global__ __launch_bounds__(256) void k_group(const float* __restrict__ X,
                                               const float* __restrict__ E,
                                               const float* __restrict__ e2,
                                               const float4* __restrict__ part4,
                                               int* __restrict__ fcount,
                                               int* __restrict__ flist,
                                               unsigned long long* __restrict__ packed,
                                               float* __restrict__ lpart,
                                               float* __restrict__ dout) {
    const int lane = threadIdx.x & 63;
    const int wave = threadIdx.x >> 6;
    const int lig = lane & 15;   // lane in row-group
    const int grp = lane >> 4;   // row-group 0..3
    const int row = blockIdx.x * 16 + wave * 4 + grp;

    // merge 4 partition records (redundant across the group's 16 lanes;
    // identical inputs -> bit-identical branch decision group-wide)
    float m1, m2;
    unsigned g;
    {
        const float4 r0 = part4[row];
        m1 = r0.x; m2 = r0.y; g = __float_as_uint(r0.z);
#pragma unroll
        for (int k = 1; k < NPART; ++k) {
            const float4 r = part4[(size_t)k * N + row];
            const unsigned rg = __float_as_uint(r.z);
            if (r.x < m1) {
                m2 = fminf(m2, m1);
                m1 = r.x;
                g = rg;
            } else {
                m2 = fminf(m2, r.x);
            }
            m2 = fminf(m2, r.y);
        }
    }

    float lossp = 0.0f;
    if (m2 - m1 < MARGIN) {  // conservative: ties & close calls -> exact scan
        if (lig == 0) {
            int p = atomicAdd(fcount, 1);
            flist[p] = row;
            packed[p] = ~0ull;
        }
    } else {
        // exact f32 rescan of winning quad: entries g*4 .. g*4+3 (consecutive)
        const int e = lig >> 2;   // entry slot 0..3 (index increases with e)
        const int dg = lig & 3;   // 16-dim segment
        const int v = (int)(g << 2) + e;
        const float4* xp = (const float4*)(X + (size_t)row * D) + dg * 4;
        float4 xa0 = xp[0], xa1 = xp[1], xa2 = xp[2], xa3 = xp[3];
        const float4* ep = (const float4*)(E + (size_t)v * D) + dg * 4;
        float4 b0 = ep[0], b1 = ep[1], b2 = ep[2], b3 = ep[3];
        float s = 0.0f;
        DOT16(s, xa0, xa1, xa2, xa3, b0, b1, b2, b3)
        s += __shfl_xor(s, 1, 64);
        s += __shfl_xor(s, 2, 64);
        float d = fmaf(-2.0f, s, e2[v]);
        int bidx = v;
#pragma unroll
        for (int off = 4; off < 16; off <<= 1) {  // across the 4 entries
            float ob = __shfl_xor(d, off, 64);
            int oi = __shfl_xor(bidx, off, 64);
            if (ob < d || (ob == d && oi < bidx)) { d = ob; bidx = oi; }
        }
        if (lig == 0) dout[IDX_OFF + row] = (float)bidx;
        // STE output + loss partial: lane lig writes dims lig*4..lig*4+3
        float4 x4 = *(const float4*)(X + (size_t)row * D + lig * 4);
        float4 q4 = *(const float4*)(E + (size_t)bidx * D + lig * 4);
        float4 o;
        o.x = x4.x + (q4.x - x4.x);
        o.y = x4.y + (q4.y - x4.y);
        o.z = x4.z + (q4.z - x4.z);
        o.w = x4.w + (q4.w - x4.w);
        *(float4*)(dout + (size_t)row * D + lig * 4) = o;
        float dx = q4.x - x4.x, dy = q4.y - x4.y, dz = q4.z - x4.z,
              dw = q4.w - x4.w;
        lossp = dx * dx + dy * dy + dz * dz + dw * dw;
    }

    // block loss partial -> lpart[bid] (plain store; summed in k_out2)
#pragma unroll
    for (int off = 32; off; off >>= 1) lossp += __shfl_down(lossp, off, 64);
    __shared__ float ps[4];
    if (lane == 0) ps[wave] = lossp;
    __syncthreads();
    if (threadIdx.x == 0) lpart[blockIdx.x] = ps[0] + ps[1] + ps[2] + ps[3];
}

// ---------------- kernel 4: exact full scan for FLAGGED rows ----------------
// work item = (row-quad, 1/8 chunk of V); grid-stride; atomicMin u64 merge.
__global__ __launch_bounds__(256) void k_full(const float* __restrict__ X,
                                              const float* __restrict__ E,
                                              const float* __restrict__ e2,
                                              const int* __restrict__ fcount,
                                              const int* __restrict__ flist,
                                              unsigned long long* __restrict__ packed) {
    const int nf = *fcount;
    if (nf == 0) return;
    const int nq = (nf + 3) >> 2;
    const int total = nq * 8;
    const int lane = threadIdx.x & 63;
    const int nwaves = gridDim.x * 4;
    int item = blockIdx.x * 4 + (threadIdx.x >> 6);
    const int e4 = lane >> 2;
    const int dg = lane & 3;

    for (; item < total; item += nwaves) {
        const int qi = item >> 3;
        const int c = item & 7;
        const int f0 = qi * 4;
        const int f1 = min(f0 + 1, nf - 1);
        const int f2 = min(f0 + 2, nf - 1);
        const int f3 = min(f0 + 3, nf - 1);
        const int r0 = flist[f0], r1 = flist[f1], r2 = flist[f2], r3 = flist[f3];

        const float4* xp0 = (const float4*)(X + (size_t)r0 * D) + dg * 4;
        const float4* xp1 = (const float4*)(X + (size_t)r1 * D) + dg * 4;
        const float4* xp2 = (const float4*)(X + (size_t)r2 * D) + dg * 4;
        const float4* xp3 = (const float4*)(X + (size_t)r3 * D) + dg * 4;
        float4 xa0 = xp0[0], xa1 = xp0[1], xa2 = xp0[2], xa3 = xp0[3];
        float4 xb0 = xp1[0], xb1 = xp1[1], xb2 = xp1[2], xb3 = xp1[3];
        float4 xc0 = xp2[0], xc1 = xp2[1], xc2 = xp2[2], xc3 = xp2[3];
        float4 xd0 = xp3[0], xd1 = xp3[1], xd2 = xp3[2], xd3 = xp3[3];

        unsigned long long k0 = ~0ull, k1 = ~0ull, k2 = ~0ull, k3 = ~0ull;

#pragma unroll 2
        for (int it = 0; it < 64; ++it) {
            const int v = c * 1024 + it * 16 + e4;
            const float4* ep = (const float4*)(E + (size_t)v * D) + dg * 4;
            float4 b0 = ep[0], b1 = ep[1], b2 = ep[2], b3 = ep[3];
            float s0 = 0.0f, s1 = 0.0f, s2 = 0.0f, s3 = 0.0f;
            DOT16(s0, xa0, xa1, xa2, xa3, b0, b1, b2, b3)
            DOT16(s1, xb0, xb1, xb2, xb3, b0, b1, b2, b3)
            DOT16(s2, xc0, xc1, xc2, xc3, b0, b1, b2, b3)
            DOT16(s3, xd0, xd1, xd2, xd3, b0, b1, b2, b3)
            s0 += __shfl_xor(s0, 1, 64); s0 += __shfl_xor(s0, 2, 64);
            s1 += __shfl_xor(s1, 1, 64); s1 += __shfl_xor(s1, 2, 64);
            s2 += __shfl_xor(s2, 1, 64); s2 += __shfl_xor(s2, 2, 64);
            s3 += __shfl_xor(s3, 1, 64); s3 += __shfl_xor(s3, 2, 64);
            const float ev = e2[v];
            const unsigned long long vb = (unsigned long long)(unsigned)v;
            unsigned long long t;
            t = ((unsigned long long)enc32(fmaf(-2.0f, s0, ev)) << 32) | vb;
            k0 = t < k0 ? t : k0;
            t = ((unsigned long long)enc32(fmaf(-2.0f, s1, ev)) << 32) | vb;
            k1 = t < k1 ? t : k1;
            t = ((unsigned long long)enc32(fmaf(-2.0f, s2, ev)) << 32) | vb;
            k2 = t < k2 ? t : k2;
            t = ((unsigned long long)enc32(fmaf(-2.0f, s3, ev)) << 32) | vb;
            k3 = t < k3 ? t : k3;
        }

#pragma unroll
        for (int off = 4; off < 64; off <<= 1) {
            unsigned lo, hi;
            unsigned long long o;
            lo = __shfl_xor((unsigned)k0, off, 64); hi = __shfl_xor((unsigned)(k0 >> 32), off, 64);
            o = ((unsigned long long)hi << 32) | lo; k0 = o < k0 ? o : k0;
            lo = __shfl_xor((unsigned)k1, off, 64); hi = __shfl_xor((unsigned)(k1 >> 32), off, 64);
            o = ((unsigned long long)hi << 32) | lo; k1 = o < k1 ? o : k1;
            lo = __shfl_xor((unsigned)k2, off, 64); hi = __shfl_xor((unsigned)(k2 >> 32), off, 64);
            o = ((unsigned long long)hi << 32) | lo; k2 = o < k2 ? o : k2;
            lo = __shfl_xor((unsigned)k3, off, 64); hi = __shfl_xor((unsigned)(k3 >> 32), off, 64);
            o = ((unsigned long long)hi << 32) | lo; k3 = o < k3 ? o : k3;
        }

        if (lane == 0) {
            atomicMin(&packed[f0], k0);
            atomicMin(&packed[f1], k1);
            atomicMin(&packed[f2], k2);
            atomicMin(&packed[f3], k3);
        }
    }
}

// ---------------- kernel 5: flagged-row epilogue + loss finalize ------------
// 64 blocks. block b: wave0 folds lpart[b*64..+63]; grid-stride waves handle
// flagged rows (idx + STE + loss); one atomicAdd per block.
__global__ __launch_bounds__(256) void k_out2(const float* __restrict__ X,
                                              const float* __restrict__ E,
                                              const int* __restrict__ fcount,
                                              const int* __restrict__ flist,
                                              const unsigned long long* __restrict__ packed,
                                              const float* __restrict__ lpart,
                                              float* __restrict__ dout) {
    const int lane = threadIdx.x & 63;
    const int wave = threadIdx.x >> 6;
    float lossp = 0.0f;
    if (wave == 0) lossp += lpart[blockIdx.x * 64 + lane];  // 64 x 64 = 4096

    const int nf = *fcount;
    const int nwaves = gridDim.x * 4;
    for (int i = blockIdx.x * 4 + wave; i < nf; i += nwaves) {
        const int row = flist[i];
        const int idx = (int)(unsigned)(packed[i] & 0xffffffffull);
        if (lane == 0) dout[IDX_OFF + row] = (float)idx;
        if (lane < 16) {
            float4 x4 = *(const float4*)(X + (size_t)row * D + lane * 4);
            float4 q4 = *(const float4*)(E + (size_t)idx * D + lane * 4);
            float4 o;
            o.x = x4.x + (q4.x - x4.x);
            o.y = x4.y + (q4.y - x4.y);
            o.z = x4.z + (q4.z - x4.z);
            o.w = x4.w + (q4.w - x4.w);
            *(float4*)(dout + (size_t)row * D + lane * 4) = o;
            float dx = q4.x - x4.x, dy = q4.y - x4.y, dz = q4.z - x4.z,
                  dw = q4.w - x4.w;
            lossp += dx * dx + dy * dy + dz * dz + dw * dw;
        }
    }

#pragma unroll
    for (int off = 32; off; off >>= 1) lossp += __shfl_down(lossp, off, 64);
    __shared__ float ps[4];
    if (lane == 0) ps[wave] = lossp;
    __syncthreads();
    if (threadIdx.x == 0) {
        float tot = ps[0] + ps[1] + ps[2] + ps[3];
        atomicAdd(dout + LOSS_OFF, tot * (1.25f / ((float)N * (float)D)));
    }
}

extern "C" void kernel_launch(void* const* d_in, const int* in_sizes, int n_in,
                              void* d_out, int out_size, void* d_ws,
                              size_t ws_size, hipStream_t stream) {
    const float* X = (const float*)d_in[0];
    const float* E = (const float*)d_in[1];
    float* out = (float*)d_out;

    char* ws = (char*)d_ws;
    _Float16* Ef16 = (_Float16*)ws;                                   // 1 MB
    float* e2 = (float*)(ws + 1048576);                               // 32 KB
    int* fcount = (int*)(ws + 1081344);                               // 256 B
    int* flist = (int*)(ws + 1081600);                                // 256 KB
    unsigned long long* packed = (unsigned long long*)(ws + 1343744); // 512 KB
    float* lpart = (float*)(ws + 1868032);                            // 16 KB
    float4* part4 = (float4*)(ws + 1933568);                          // 4 MB

    k_split<<<256, 256, 0, stream>>>(E, Ef16, e2, out, fcount);
    k_argmin<<<(N / 256) * NPART, 512, 0, stream>>>(X, Ef16, e2, part4);
    k_group<<<N / 16, 256, 0, stream>>>(X, E, e2, part4, fcount, flist, packed, lpart, out);
    k_full<<<1024, 256, 0, stream>>>(X, E, e2, fcount, flist, packed);
    k_out2<<<64, 256, 0, stream>>>(X, E, fcount, flist, packed, lpart, out);
}